// Round 7
// baseline (453.559 us; speedup 1.0000x reference)
//
#include <hip/hip_runtime.h>
#include <hip/hip_fp16.h>
#include <math.h>

#define N_GRAPHS 100
#define HCHUNK 32768
#define HBLK 32

typedef _Float16 f16x8 __attribute__((ext_vector_type(8)));
typedef __attribute__((ext_vector_type(4))) float f32x4;

__device__ __forceinline__ float lrelu(float v) { return v >= 0.f ? v : 0.1f * v; }

// ---------------- chunked LDS histogram: per-block counts to scratch ----------------
__global__ __launch_bounds__(512, 1)
void k_hist(const int* __restrict__ keys, int* __restrict__ scratch, int E) {
    __shared__ int h[HCHUNK];   // 128 KiB
    const int c = blockIdx.x / HBLK;
    const int b = blockIdx.x % HBLK;
    const int base = c * HCHUNK;
    for (int i = threadIdx.x; i < HCHUNK; i += 512) h[i] = 0;
    __syncthreads();
    for (int i = b * 512 + threadIdx.x; i < E; i += HBLK * 512) {
        unsigned k = (unsigned)(keys[i] - base);
        if (k < HCHUNK) atomicAdd(&h[k], 1);
    }
    __syncthreads();
    int* outp = scratch + (size_t)blockIdx.x * HCHUNK;
    for (int i = threadIdx.x; i < HCHUNK; i += 512) outp[i] = h[i];
}

template <int WRITE_INT>
__global__ void k_hist_reduce(const int* __restrict__ scratch, int* __restrict__ deg_out,
                              float* __restrict__ dinv_out, int N) {
    int g = blockIdx.x * blockDim.x + threadIdx.x;
    if (g >= N) return;
    const int c = g >> 15;
    const int p = g & (HCHUNK - 1);
    const int* col = scratch + ((size_t)(c * HBLK)) * HCHUNK + p;
    int s = 0;
#pragma unroll 8
    for (int b = 0; b < HBLK; ++b) s += col[(size_t)b * HCHUNK];
    if (WRITE_INT) deg_out[g] = s;
    dinv_out[g] = rsqrtf(fmaxf((float)s, 1.0f));
}

// ---------------- fold W3 @ Wout -> w[128], c = b3.Wout + bout ----------------
__global__ void k_fold_w(const float* __restrict__ W3, const float* __restrict__ b3,
                         const float* __restrict__ Wout, const float* __restrict__ bout,
                         float* __restrict__ w, float* __restrict__ cval) {
    int i = threadIdx.x; // 128 threads
    float s = 0.f;
    for (int j = 0; j < 64; ++j) s += W3[i * 64 + j] * Wout[j];
    w[i] = s;
    if (i == 0) {
        float c = bout[0];
        for (int j = 0; j < 64; ++j) c += b3[j] * Wout[j];
        *cval = c;
    }
}

// ---------------- convert W (128x128 fp32) -> transposed+swizzled fp16 ----------------
// element (col,k) stored at col*128 + (k ^ ((col&15)<<3))
__global__ void k_wconv(const float* __restrict__ W, __half* __restrict__ wT) {
    int t = threadIdx.x;
    for (int i = t; i < 16384; i += 256) {
        int k = i >> 7, col = i & 127;
        wT[col * 128 + (k ^ ((col & 15) << 3))] = __float2half(W[i]);
    }
}

// ---------------- exclusive scan over degd -> off (3-kernel) ----------------
__global__ void k_scanA(const int* __restrict__ deg, int* __restrict__ off,
                        int* __restrict__ partials, int N) {
    __shared__ int ts[256];
    const int t = threadIdx.x;
    const int base = blockIdx.x * 1024 + t * 4;
    int v0 = (base + 0 < N) ? deg[base + 0] : 0;
    int v1 = (base + 1 < N) ? deg[base + 1] : 0;
    int v2 = (base + 2 < N) ? deg[base + 2] : 0;
    int v3 = (base + 3 < N) ? deg[base + 3] : 0;
    int s = v0 + v1 + v2 + v3;
    ts[t] = s;
    __syncthreads();
    for (int o = 1; o < 256; o <<= 1) {
        int y = (t >= o) ? ts[t - o] : 0;
        __syncthreads();
        ts[t] += y;
        __syncthreads();
    }
    int excl = ts[t] - s;
    if (base + 0 < N) off[base + 0] = excl;
    if (base + 1 < N) off[base + 1] = excl + v0;
    if (base + 2 < N) off[base + 2] = excl + v0 + v1;
    if (base + 3 < N) off[base + 3] = excl + v0 + v1 + v2;
    if (t == 255) partials[blockIdx.x] = ts[255];
}

__global__ void k_scanB(int* __restrict__ partials, int nb) {
    __shared__ int ps[256];
    const int t = threadIdx.x;
    int v = (t < nb) ? partials[t] : 0;
    ps[t] = v;
    __syncthreads();
    for (int o = 1; o < 256; o <<= 1) {
        int y = (t >= o) ? ps[t - o] : 0;
        __syncthreads();
        ps[t] += y;
        __syncthreads();
    }
    if (t < nb) partials[t] = ps[t] - v;
}

__global__ void k_scanC(int* __restrict__ off, const int* __restrict__ partials, int N, int E) {
    const int t = threadIdx.x;
    const int base = blockIdx.x * 1024 + t * 4;
    const int add = partials[blockIdx.x];
#pragma unroll
    for (int q = 0; q < 4; ++q) {
        int idx = base + q;
        if (idx < N) off[idx] += add;
    }
    if (blockIdx.x == 0 && t == 0) off[N] = E;
}

// ---------------- column-scan per-block counts -> per-block cursors ----------------
__global__ void k_colscan(int* __restrict__ scratch, const int* __restrict__ off,
                          int NBINS, int N) {
    int g = blockIdx.x * blockDim.x + threadIdx.x;
    if (g >= NBINS) return;
    const int c = g >> 15;
    const int p = g & (HCHUNK - 1);
    int* col = scratch + ((size_t)(c * HBLK)) * HCHUNK + p;
    int run = (g < N) ? off[g] : 0;
    for (int b = 0; b < HBLK; ++b) {
        int* q = col + (size_t)b * HCHUNK;
        int t = *q;
        *q = run;
        run += t;
    }
}

// ---------------- atomic-free(global) CSR fill via LDS cursors ----------------
__global__ __launch_bounds__(512, 1)
void k_csrfill2(const int* __restrict__ src, const int* __restrict__ dst,
                const int* __restrict__ scratch, int* __restrict__ csr, int E) {
    __shared__ int cur[HCHUNK];   // 128 KiB
    const int c = blockIdx.x / HBLK;
    const int b = blockIdx.x % HBLK;
    const int base = c * HCHUNK;
    const int* my = scratch + (size_t)(c * HBLK + b) * HCHUNK;
    for (int i = threadIdx.x; i < HCHUNK; i += 512) cur[i] = my[i];
    __syncthreads();
    for (int i = b * 512 + threadIdx.x; i < E; i += HBLK * 512) {
        unsigned k = (unsigned)(dst[i] - base);
        if (k < HCHUNK) {
            int p = atomicAdd(&cur[k], 1);
            csr[p] = src[i];
        }
    }
}

// ---------------- fp16 MFMA GEMM:  M = X @ W ----------------
// PRE==2: X fp32, prenorm x*dinv_src (layer 1).  PRE==0: X fp16, pure GEMM.
// LDS element (row,k) of X at row*128 + (k ^ ((row&15)<<3)); same for W by col.
template <int PRE>
__global__ __launch_bounds__(512, 2)
void k_gemm_mfma(const void* __restrict__ Xv, __half* __restrict__ Y,
                 const __half* __restrict__ wT, const float* __restrict__ dinv_src,
                 int N) {
    __shared__ __half Xs[128 * 128];  // 32 KiB
    __shared__ __half Ws[128 * 128];  // 32 KiB
    const int t = threadIdx.x;
    const int r0 = blockIdx.x * 128;

    for (int i = t; i < 2048; i += 512) ((float4*)Ws)[i] = ((const float4*)wT)[i];

    if (PRE == 2) {
        const float* X = (const float*)Xv;
        for (int i = t; i < 4096; i += 512) {
            int row = i >> 5;
            int g4 = (i & 31) << 2;
            int grow = r0 + row;
            float4 v = make_float4(0.f, 0.f, 0.f, 0.f);
            if (grow < N) {
                v = ((const float4*)(X + (size_t)grow * 128))[i & 31];
                float ds = dinv_src[grow];
                v.x *= ds; v.y *= ds; v.z *= ds; v.w *= ds;
            }
            union { float2 f; __half2 h[2]; } pk;
            pk.h[0] = __floats2half2_rn(v.x, v.y);
            pk.h[1] = __floats2half2_rn(v.z, v.w);
            *(float2*)&Xs[row * 128 + (g4 ^ ((row & 15) << 3))] = pk.f;
        }
    } else {
        const __half* X = (const __half*)Xv;
        for (int i = t; i < 2048; i += 512) {
            int row = i >> 4;
            int g8 = (i & 15) << 3;
            int grow = r0 + row;
            uint4 v = make_uint4(0u, 0u, 0u, 0u);
            if (grow < N) v = ((const uint4*)(X + (size_t)grow * 128))[i & 15];
            *(uint4*)&Xs[row * 128 + (g8 ^ ((row & 15) << 3))] = v;
        }
    }
    __syncthreads();

    const int w = t >> 6;
    const int wm = w & 3;          // rows 32*wm..+31
    const int wn = w >> 2;         // cols 64*wn..+63
    const int lane = t & 63;
    const int lr = lane & 15;
    const int lg = lane >> 4;

    f32x4 acc[2][4];
#pragma unroll
    for (int mi = 0; mi < 2; ++mi)
#pragma unroll
        for (int ni = 0; ni < 4; ++ni) acc[mi][ni] = (f32x4){0.f, 0.f, 0.f, 0.f};

#pragma unroll
    for (int ks = 0; ks < 4; ++ks) {
        const int k0 = 32 * ks + 4 * lg;
        union F { float2 f[2]; f16x8 v; };
        F a[2];
#pragma unroll
        for (int mi = 0; mi < 2; ++mi) {
            int row = 32 * wm + 16 * mi + lr;
            int sw = (row & 15) << 3;
            a[mi].f[0] = *(const float2*)&Xs[row * 128 + (k0 ^ sw)];
            a[mi].f[1] = *(const float2*)&Xs[row * 128 + ((k0 + 16) ^ sw)];
        }
#pragma unroll
        for (int ni = 0; ni < 4; ++ni) {
            int colv = 64 * wn + 16 * ni + lr;
            int sw = (colv & 15) << 3;
            F b;
            b.f[0] = *(const float2*)&Ws[colv * 128 + (k0 ^ sw)];
            b.f[1] = *(const float2*)&Ws[colv * 128 + ((k0 + 16) ^ sw)];
#pragma unroll
            for (int mi = 0; mi < 2; ++mi) {
                acc[mi][ni] = __builtin_amdgcn_mfma_f32_16x16x32_f16(a[mi].v, b.v, acc[mi][ni], 0, 0, 0);
            }
        }
    }

    // epilogue: bounce C through LDS (reuse Xs) for coalesced 16B stores
    __syncthreads();
#pragma unroll
    for (int mi = 0; mi < 2; ++mi)
#pragma unroll
        for (int r = 0; r < 4; ++r) {
            int row = 32 * wm + 16 * mi + 4 * lg + r;
#pragma unroll
            for (int ni = 0; ni < 4; ++ni)
                Xs[row * 128 + 64 * wn + 16 * ni + lr] = __float2half(acc[mi][ni][r]);
        }
    __syncthreads();
    for (int i = t; i < 2048; i += 512) {
        int row = i >> 4;
        int grow = r0 + row;
        if (grow < N) {
            int col8 = (i & 15) << 3;
            *(uint4*)(Y + (size_t)grow * 128 + col8) = *(const uint4*)&Xs[row * 128 + col8];
        }
    }
}

// ---------------- CSR gather (fp16 msgs), half-wave per node, 8-edge unroll ----------
// EPI==0: H[n] = fp16( lrelu(agg*ddst + bias) * dsrc )   (fused act + next prenorm)
// EPI==1: tv[n] = dsrc * ( lrelu(agg*ddst + bias) . wfold )  (folded conv3 + readout)
template <int EPI>
__global__ __launch_bounds__(256)
void k_gather_h(const __half* __restrict__ T, __half* __restrict__ Hout,
                const int* __restrict__ csr, const int* __restrict__ off, int N,
                const float* __restrict__ ddst, const float* __restrict__ bias,
                const float* __restrict__ dsrc, const float* __restrict__ wfold,
                float* __restrict__ tv) {
    int n = blockIdx.x * 8 + (threadIdx.x >> 5);
    if (n >= N) return;
    const int lane = threadIdx.x & 31;
    const int c = lane << 2;      // 4 halfs per lane (8 B)
    int j = off[n];
    const int jend = off[n + 1];
    float4 a0 = make_float4(0.f, 0.f, 0.f, 0.f);
    float4 a1 = make_float4(0.f, 0.f, 0.f, 0.f);
    float4 a2 = make_float4(0.f, 0.f, 0.f, 0.f);
    float4 a3 = make_float4(0.f, 0.f, 0.f, 0.f);
    union H4 { float2 raw; __half2 hh[2]; };
    for (; j + 8 <= jend; j += 8) {
        int e0 = csr[j], e1 = csr[j + 1], e2 = csr[j + 2], e3 = csr[j + 3];
        int e4 = csr[j + 4], e5 = csr[j + 5], e6 = csr[j + 6], e7 = csr[j + 7];
        H4 v0, v1, v2, v3, v4, v5, v6, v7;
        v0.raw = *(const float2*)(T + (size_t)e0 * 128 + c);
        v1.raw = *(const float2*)(T + (size_t)e1 * 128 + c);
        v2.raw = *(const float2*)(T + (size_t)e2 * 128 + c);
        v3.raw = *(const float2*)(T + (size_t)e3 * 128 + c);
        v4.raw = *(const float2*)(T + (size_t)e4 * 128 + c);
        v5.raw = *(const float2*)(T + (size_t)e5 * 128 + c);
        v6.raw = *(const float2*)(T + (size_t)e6 * 128 + c);
        v7.raw = *(const float2*)(T + (size_t)e7 * 128 + c);
        float2 x0 = __half22float2(v0.hh[0]), y0 = __half22float2(v0.hh[1]);
        float2 x1 = __half22float2(v1.hh[0]), y1 = __half22float2(v1.hh[1]);
        float2 x2 = __half22float2(v2.hh[0]), y2 = __half22float2(v2.hh[1]);
        float2 x3 = __half22float2(v3.hh[0]), y3 = __half22float2(v3.hh[1]);
        float2 x4 = __half22float2(v4.hh[0]), y4 = __half22float2(v4.hh[1]);
        float2 x5 = __half22float2(v5.hh[0]), y5 = __half22float2(v5.hh[1]);
        float2 x6 = __half22float2(v6.hh[0]), y6 = __half22float2(v6.hh[1]);
        float2 x7 = __half22float2(v7.hh[0]), y7 = __half22float2(v7.hh[1]);
        a0.x += x0.x + x1.x; a0.y += x0.y + x1.y; a0.z += y0.x + y1.x; a0.w += y0.y + y1.y;
        a1.x += x2.x + x3.x; a1.y += x2.y + x3.y; a1.z += y2.x + y3.x; a1.w += y2.y + y3.y;
        a2.x += x4.x + x5.x; a2.y += x4.y + x5.y; a2.z += y4.x + y5.x; a2.w += y4.y + y5.y;
        a3.x += x6.x + x7.x; a3.y += x6.y + x7.y; a3.z += y6.x + y7.x; a3.w += y6.y + y7.y;
    }
    for (; j < jend; ++j) {
        int e0 = csr[j];
        H4 v0;
        v0.raw = *(const float2*)(T + (size_t)e0 * 128 + c);
        float2 x0 = __half22float2(v0.hh[0]), y0 = __half22float2(v0.hh[1]);
        a0.x += x0.x; a0.y += x0.y; a0.z += y0.x; a0.w += y0.y;
    }
    float4 a = make_float4(a0.x + a1.x + a2.x + a3.x, a0.y + a1.y + a2.y + a3.y,
                           a0.z + a1.z + a2.z + a3.z, a0.w + a1.w + a2.w + a3.w);
    float dd = ddst[n];
    float ds = dsrc[n];
    float h0 = lrelu(a.x * dd + bias[c + 0]);
    float h1 = lrelu(a.y * dd + bias[c + 1]);
    float h2 = lrelu(a.z * dd + bias[c + 2]);
    float h3 = lrelu(a.w * dd + bias[c + 3]);
    if (EPI == 0) {
        union H4 o;
        o.hh[0] = __floats2half2_rn(h0 * ds, h1 * ds);
        o.hh[1] = __floats2half2_rn(h2 * ds, h3 * ds);
        *(float2*)(Hout + (size_t)n * 128 + c) = o.raw;
    } else {
        float s = h0 * wfold[c + 0] + h1 * wfold[c + 1] + h2 * wfold[c + 2] + h3 * wfold[c + 3];
#pragma unroll
        for (int o = 16; o > 0; o >>= 1) s += __shfl_xor(s, o);
        if (lane == 0) tv[n] = s * ds;
    }
}

// ---------------- final: z[n]=sum tv[csr], s=z*ddst+c, per-graph mean bins ----------------
__global__ void k_gather_final(const float* __restrict__ tv, const int* __restrict__ csr,
                               const int* __restrict__ off, const float* __restrict__ ddst,
                               const int* __restrict__ gid, const float* __restrict__ cval,
                               float* __restrict__ gsum, float* __restrict__ gcnt, int N) {
    __shared__ float sb[N_GRAPHS], sc[N_GRAPHS];
    for (int i = threadIdx.x; i < N_GRAPHS; i += blockDim.x) { sb[i] = 0.f; sc[i] = 0.f; }
    __syncthreads();
    int n = blockIdx.x * blockDim.x + threadIdx.x;
    if (n < N) {
        int j = off[n], jend = off[n + 1];
        float z = 0.f;
        for (; j < jend; ++j) z += tv[csr[j]];
        float s = z * ddst[n] + cval[0];
        int g = gid[n];
        atomicAdd(&sb[g], s);
        atomicAdd(&sc[g], 1.f);
    }
    __syncthreads();
    for (int j = threadIdx.x; j < N_GRAPHS; j += blockDim.x) {
        if (sc[j] != 0.f) {
            atomicAdd(&gsum[j], sb[j]);
            atomicAdd(&gcnt[j], sc[j]);
        }
    }
}

__global__ void k_final(const float* __restrict__ gsum, const float* __restrict__ gcnt,
                        float* __restrict__ out) {
    int g = threadIdx.x;
    if (g < N_GRAPHS) out[g] = gsum[g] / fmaxf(gcnt[g], 1.0f);
}

extern "C" void kernel_launch(void* const* d_in, const int* in_sizes, int n_in,
                              void* d_out, int out_size, void* d_ws, size_t ws_size,
                              hipStream_t stream) {
    const float* in_feat = (const float*)d_in[0];
    const float* W1   = (const float*)d_in[1];
    const float* b1   = (const float*)d_in[2];
    const float* W2   = (const float*)d_in[3];
    const float* b2   = (const float*)d_in[4];
    const float* W3   = (const float*)d_in[5];
    const float* b3   = (const float*)d_in[6];
    const float* Wout = (const float*)d_in[7];
    const float* bout = (const float*)d_in[8];
    const int* src = (const int*)d_in[9];
    const int* dst = (const int*)d_in[10];
    const int* gid = (const int*)d_in[11];
    const int N = in_sizes[0] / 128;
    const int E = in_sizes[9];
    float* out = (float*)d_out;

    char* ws = (char*)d_ws;
    size_t woff = 0;
    auto alloc = [&](size_t bytes) {
        void* p = ws + woff;
        woff = (woff + bytes + 255) & ~(size_t)255;
        return p;
    };
    const int nchunks = (N + HCHUNK - 1) / HCHUNK;         // 4 for N=100000
    const int NBINS = nchunks * HCHUNK;
    size_t scratch_bytes = (size_t)NBINS * HBLK * 4;       // 16.8 MB
    size_t msg_bytes = (size_t)N * 128 * 2;                // 25.6 MB
    // M (fp16 messages) aliases histogram scratch: scratch dead after k_csrfill2.
    void* region0 = alloc(scratch_bytes > msg_bytes ? scratch_bytes : msg_bytes);
    int*    scratch = (int*)region0;
    __half* M       = (__half*)region0;
    __half* H    = (__half*)alloc(msg_bytes);              // pre-normed activations
    int*   csr   = (int*)alloc((size_t)E * 4);
    int*   degd  = (int*)alloc((size_t)N * 4);
    int*   off   = (int*)alloc((size_t)(N + 1) * 4);
    int*   partials = (int*)alloc(256 * 4);
    float* dsrc  = (float*)alloc((size_t)N * 4);
    float* ddst  = (float*)alloc((size_t)N * 4);
    float* tv    = (float*)alloc((size_t)N * 4);
    float* wfold = (float*)alloc(128 * 4);
    float* cval  = (float*)alloc(4);
    float* gsum  = (float*)alloc(N_GRAPHS * 4);
    float* gcnt  = (float*)alloc(N_GRAPHS * 4);
    __half* w1T  = (__half*)alloc(16384 * 2);
    __half* w2T  = (__half*)alloc(16384 * 2);
    (void)ws_size; (void)n_in; (void)out_size;

    hipMemsetAsync(gsum, 0, N_GRAPHS * 4, stream);
    hipMemsetAsync(gcnt, 0, N_GRAPHS * 4, stream);

    k_fold_w<<<1, 128, 0, stream>>>(W3, b3, Wout, bout, wfold, cval);
    k_wconv<<<1, 256, 0, stream>>>(W1, w1T);
    k_wconv<<<1, 256, 0, stream>>>(W2, w2T);

    // degrees via chunked LDS histograms (no global atomics)
    k_hist<<<nchunks * HBLK, 512, 0, stream>>>(src, scratch, E);
    k_hist_reduce<0><<<(N + 255) / 256, 256, 0, stream>>>(scratch, nullptr, dsrc, N);
    k_hist<<<nchunks * HBLK, 512, 0, stream>>>(dst, scratch, E);
    k_hist_reduce<1><<<(N + 255) / 256, 256, 0, stream>>>(scratch, degd, ddst, N);

    // CSR offsets
    const int nscan = (N + 1023) / 1024;
    k_scanA<<<nscan, 256, 0, stream>>>(degd, off, partials, N);
    k_scanB<<<1, 256, 0, stream>>>(partials, nscan);
    k_scanC<<<nscan, 256, 0, stream>>>(off, partials, N, E);

    // per-block cursors, then counting-sort fill (LDS atomics only)
    k_colscan<<<(NBINS + 255) / 256, 256, 0, stream>>>(scratch, off, NBINS, N);
    k_csrfill2<<<nchunks * HBLK, 512, 0, stream>>>(src, dst, scratch, csr, E);

    const int gblocks = (N + 127) / 128;
    const int agblocks = (N + 7) / 8;

    // layer 1: M = (in_feat * dsrc) @ W1 ; H = prenorm(gather(M), b1)
    k_gemm_mfma<2><<<gblocks, 512, 0, stream>>>(in_feat, M, w1T, dsrc, N);
    k_gather_h<0><<<agblocks, 256, 0, stream>>>(M, H, csr, off, N, ddst, b1, dsrc, nullptr, nullptr);

    // layer 2: M = H @ W2 ; H = prenorm(gather(M), b2)
    k_gemm_mfma<0><<<gblocks, 512, 0, stream>>>(H, M, w2T, nullptr, N);
    k_gather_h<0><<<agblocks, 256, 0, stream>>>(M, H, csr, off, N, ddst, b2, dsrc, nullptr, nullptr);

    // layer 3 (conv2 again): M = H @ W2 ; fused readout gather -> tv
    k_gemm_mfma<0><<<gblocks, 512, 0, stream>>>(H, M, w2T, nullptr, N);
    k_gather_h<1><<<agblocks, 256, 0, stream>>>(M, nullptr, csr, off, N, ddst, b2, dsrc, wfold, tv);

    // readout aggregation + per-graph mean
    k_gather_final<<<(N + 255) / 256, 256, 0, stream>>>(tv, csr, off, ddst, gid, cval, gsum, gcnt, N);
    k_final<<<1, 128, 0, stream>>>(gsum, gcnt, out);
}

// Round 8
// 431.651 us; speedup vs baseline: 1.0508x; 1.0508x over previous
//
#include <hip/hip_runtime.h>
#include <hip/hip_fp16.h>
#include <math.h>

#define N_GRAPHS 100
#define HCHUNK 32768
#define HBLK 64

typedef _Float16 f16x8 __attribute__((ext_vector_type(8)));
typedef __attribute__((ext_vector_type(4))) float f32x4;

__device__ __forceinline__ float lrelu(float v) { return v >= 0.f ? v : 0.1f * v; }

// ---------------- chunked LDS histogram: per-block counts to scratch ----------------
__global__ __launch_bounds__(512, 1)
void k_hist(const int* __restrict__ keys, int* __restrict__ scratch, int E) {
    __shared__ int h[HCHUNK];   // 128 KiB
    const int c = blockIdx.x / HBLK;
    const int b = blockIdx.x % HBLK;
    const int base = c * HCHUNK;
    for (int i = threadIdx.x; i < HCHUNK; i += 512) h[i] = 0;
    __syncthreads();
    for (int i = b * 512 + threadIdx.x; i < E; i += HBLK * 512) {
        unsigned k = (unsigned)(keys[i] - base);
        if (k < HCHUNK) atomicAdd(&h[k], 1);
    }
    __syncthreads();
    int* outp = scratch + (size_t)blockIdx.x * HCHUNK;
    for (int i = threadIdx.x; i < HCHUNK; i += 512) outp[i] = h[i];
}

template <int WRITE_INT>
__global__ void k_hist_reduce(const int* __restrict__ scratch, int* __restrict__ deg_out,
                              float* __restrict__ dinv_out, int N) {
    int g = blockIdx.x * blockDim.x + threadIdx.x;
    if (g >= N) return;
    const int c = g >> 15;
    const int p = g & (HCHUNK - 1);
    const int* col = scratch + ((size_t)(c * HBLK)) * HCHUNK + p;
    int s = 0;
#pragma unroll 8
    for (int b = 0; b < HBLK; ++b) s += col[(size_t)b * HCHUNK];
    if (WRITE_INT) deg_out[g] = s;
    dinv_out[g] = rsqrtf(fmaxf((float)s, 1.0f));
}

// ---------------- fold W3 @ Wout -> w[128], c = b3.Wout + bout ----------------
__global__ void k_fold_w(const float* __restrict__ W3, const float* __restrict__ b3,
                         const float* __restrict__ Wout, const float* __restrict__ bout,
                         float* __restrict__ w, float* __restrict__ cval) {
    int i = threadIdx.x; // 128 threads
    float s = 0.f;
    for (int j = 0; j < 64; ++j) s += W3[i * 64 + j] * Wout[j];
    w[i] = s;
    if (i == 0) {
        float c = bout[0];
        for (int j = 0; j < 64; ++j) c += b3[j] * Wout[j];
        *cval = c;
    }
}

// ---------------- convert W (128x128 fp32) -> transposed+swizzled fp16 ----------------
// element (col,k) stored at col*128 + (k ^ ((col&15)<<3))
__global__ void k_wconv(const float* __restrict__ W, __half* __restrict__ wT) {
    int t = threadIdx.x;
    for (int i = t; i < 16384; i += 256) {
        int k = i >> 7, col = i & 127;
        wT[col * 128 + (k ^ ((col & 15) << 3))] = __float2half(W[i]);
    }
}

// ---------------- exclusive scan over degd -> off (3-kernel) ----------------
__global__ void k_scanA(const int* __restrict__ deg, int* __restrict__ off,
                        int* __restrict__ partials, int N) {
    __shared__ int ts[256];
    const int t = threadIdx.x;
    const int base = blockIdx.x * 1024 + t * 4;
    int v0 = (base + 0 < N) ? deg[base + 0] : 0;
    int v1 = (base + 1 < N) ? deg[base + 1] : 0;
    int v2 = (base + 2 < N) ? deg[base + 2] : 0;
    int v3 = (base + 3 < N) ? deg[base + 3] : 0;
    int s = v0 + v1 + v2 + v3;
    ts[t] = s;
    __syncthreads();
    for (int o = 1; o < 256; o <<= 1) {
        int y = (t >= o) ? ts[t - o] : 0;
        __syncthreads();
        ts[t] += y;
        __syncthreads();
    }
    int excl = ts[t] - s;
    if (base + 0 < N) off[base + 0] = excl;
    if (base + 1 < N) off[base + 1] = excl + v0;
    if (base + 2 < N) off[base + 2] = excl + v0 + v1;
    if (base + 3 < N) off[base + 3] = excl + v0 + v1 + v2;
    if (t == 255) partials[blockIdx.x] = ts[255];
}

__global__ void k_scanB(int* __restrict__ partials, int nb) {
    __shared__ int ps[256];
    const int t = threadIdx.x;
    int v = (t < nb) ? partials[t] : 0;
    ps[t] = v;
    __syncthreads();
    for (int o = 1; o < 256; o <<= 1) {
        int y = (t >= o) ? ps[t - o] : 0;
        __syncthreads();
        ps[t] += y;
        __syncthreads();
    }
    if (t < nb) partials[t] = ps[t] - v;
}

__global__ void k_scanC(int* __restrict__ off, const int* __restrict__ partials, int N, int E) {
    const int t = threadIdx.x;
    const int base = blockIdx.x * 1024 + t * 4;
    const int add = partials[blockIdx.x];
#pragma unroll
    for (int q = 0; q < 4; ++q) {
        int idx = base + q;
        if (idx < N) off[idx] += add;
    }
    if (blockIdx.x == 0 && t == 0) off[N] = E;
}

// ---------------- column-scan per-block counts -> per-block cursors ----------------
__global__ void k_colscan(int* __restrict__ scratch, const int* __restrict__ off,
                          int NBINS, int N) {
    int g = blockIdx.x * blockDim.x + threadIdx.x;
    if (g >= NBINS) return;
    const int c = g >> 15;
    const int p = g & (HCHUNK - 1);
    int* col = scratch + ((size_t)(c * HBLK)) * HCHUNK + p;
    int run = (g < N) ? off[g] : 0;
    for (int b = 0; b < HBLK; ++b) {
        int* q = col + (size_t)b * HCHUNK;
        int t = *q;
        *q = run;
        run += t;
    }
}

// ---------------- atomic-free(global) CSR fill via LDS cursors ----------------
__global__ __launch_bounds__(512, 1)
void k_csrfill2(const int* __restrict__ src, const int* __restrict__ dst,
                const int* __restrict__ scratch, int* __restrict__ csr, int E) {
    __shared__ int cur[HCHUNK];   // 128 KiB
    const int c = blockIdx.x / HBLK;
    const int b = blockIdx.x % HBLK;
    const int base = c * HCHUNK;
    const int* my = scratch + (size_t)(c * HBLK + b) * HCHUNK;
    for (int i = threadIdx.x; i < HCHUNK; i += 512) cur[i] = my[i];
    __syncthreads();
    for (int i = b * 512 + threadIdx.x; i < E; i += HBLK * 512) {
        unsigned k = (unsigned)(dst[i] - base);
        if (k < HCHUNK) {
            int p = atomicAdd(&cur[k], 1);
            csr[p] = src[i];
        }
    }
}

// ---------------- fp16 MFMA GEMM:  M = X @ W ----------------
// PRE==2: X fp32, prenorm x*dinv_src (layer 1).  PRE==0: X fp16, pure GEMM.
template <int PRE>
__global__ __launch_bounds__(512, 2)
void k_gemm_mfma(const void* __restrict__ Xv, __half* __restrict__ Y,
                 const __half* __restrict__ wT, const float* __restrict__ dinv_src,
                 int N) {
    __shared__ __half Xs[128 * 128];  // 32 KiB
    __shared__ __half Ws[128 * 128];  // 32 KiB
    const int t = threadIdx.x;
    const int r0 = blockIdx.x * 128;

    for (int i = t; i < 2048; i += 512) ((float4*)Ws)[i] = ((const float4*)wT)[i];

    if (PRE == 2) {
        const float* X = (const float*)Xv;
        for (int i = t; i < 4096; i += 512) {
            int row = i >> 5;
            int g4 = (i & 31) << 2;
            int grow = r0 + row;
            float4 v = make_float4(0.f, 0.f, 0.f, 0.f);
            if (grow < N) {
                v = ((const float4*)(X + (size_t)grow * 128))[i & 31];
                float ds = dinv_src[grow];
                v.x *= ds; v.y *= ds; v.z *= ds; v.w *= ds;
            }
            union { float2 f; __half2 h[2]; } pk;
            pk.h[0] = __floats2half2_rn(v.x, v.y);
            pk.h[1] = __floats2half2_rn(v.z, v.w);
            *(float2*)&Xs[row * 128 + (g4 ^ ((row & 15) << 3))] = pk.f;
        }
    } else {
        const __half* X = (const __half*)Xv;
        for (int i = t; i < 2048; i += 512) {
            int row = i >> 4;
            int g8 = (i & 15) << 3;
            int grow = r0 + row;
            uint4 v = make_uint4(0u, 0u, 0u, 0u);
            if (grow < N) v = ((const uint4*)(X + (size_t)grow * 128))[i & 15];
            *(uint4*)&Xs[row * 128 + (g8 ^ ((row & 15) << 3))] = v;
        }
    }
    __syncthreads();

    const int w = t >> 6;
    const int wm = w & 3;          // rows 32*wm..+31
    const int wn = w >> 2;         // cols 64*wn..+63
    const int lane = t & 63;
    const int lr = lane & 15;
    const int lg = lane >> 4;

    f32x4 acc[2][4];
#pragma unroll
    for (int mi = 0; mi < 2; ++mi)
#pragma unroll
        for (int ni = 0; ni < 4; ++ni) acc[mi][ni] = (f32x4){0.f, 0.f, 0.f, 0.f};

#pragma unroll
    for (int ks = 0; ks < 4; ++ks) {
        const int k0 = 32 * ks + 4 * lg;
        union F { float2 f[2]; f16x8 v; };
        F a[2];
#pragma unroll
        for (int mi = 0; mi < 2; ++mi) {
            int row = 32 * wm + 16 * mi + lr;
            int sw = (row & 15) << 3;
            a[mi].f[0] = *(const float2*)&Xs[row * 128 + (k0 ^ sw)];
            a[mi].f[1] = *(const float2*)&Xs[row * 128 + ((k0 + 16) ^ sw)];
        }
#pragma unroll
        for (int ni = 0; ni < 4; ++ni) {
            int colv = 64 * wn + 16 * ni + lr;
            int sw = (colv & 15) << 3;
            F b;
            b.f[0] = *(const float2*)&Ws[colv * 128 + (k0 ^ sw)];
            b.f[1] = *(const float2*)&Ws[colv * 128 + ((k0 + 16) ^ sw)];
#pragma unroll
            for (int mi = 0; mi < 2; ++mi) {
                acc[mi][ni] = __builtin_amdgcn_mfma_f32_16x16x32_f16(a[mi].v, b.v, acc[mi][ni], 0, 0, 0);
            }
        }
    }

    // epilogue: bounce C through LDS (reuse Xs) for coalesced 16B stores
    __syncthreads();
#pragma unroll
    for (int mi = 0; mi < 2; ++mi)
#pragma unroll
        for (int r = 0; r < 4; ++r) {
            int row = 32 * wm + 16 * mi + 4 * lg + r;
#pragma unroll
            for (int ni = 0; ni < 4; ++ni)
                Xs[row * 128 + 64 * wn + 16 * ni + lr] = __float2half(acc[mi][ni][r]);
        }
    __syncthreads();
    for (int i = t; i < 2048; i += 512) {
        int row = i >> 4;
        int grow = r0 + row;
        if (grow < N) {
            int col8 = (i & 15) << 3;
            *(uint4*)(Y + (size_t)grow * 128 + col8) = *(const uint4*)&Xs[row * 128 + col8];
        }
    }
}

// ---------------- CSR gather (fp16 msgs), 16-lane group per node, 16B/lane ----------
// EPI==0: H[n] = fp16( lrelu(agg*ddst + bias) * dsrc )   (fused act + next prenorm)
// EPI==1: tv[n] = dsrc * ( lrelu(agg*ddst + bias) . wfold )  (folded conv3 + readout)
template <int EPI>
__global__ __launch_bounds__(256)
void k_gather_h(const __half* __restrict__ T, __half* __restrict__ Hout,
                const int* __restrict__ csr, const int* __restrict__ off, int N,
                const float* __restrict__ ddst, const float* __restrict__ bias,
                const float* __restrict__ dsrc, const float* __restrict__ wfold,
                float* __restrict__ tv) {
    int n = blockIdx.x * 16 + (threadIdx.x >> 4);
    if (n >= N) return;
    const int lane = threadIdx.x & 15;
    const int c = lane << 3;      // 8 halfs per lane (16 B)
    int j = off[n];
    const int jend = off[n + 1];
    float a0[8], a1[8], a2[8], a3[8];
#pragma unroll
    for (int q = 0; q < 8; ++q) { a0[q] = 0.f; a1[q] = 0.f; a2[q] = 0.f; a3[q] = 0.f; }
    union HV { uint4 u; __half2 h[4]; };
    for (; j + 8 <= jend; j += 8) {
        int e0 = csr[j], e1 = csr[j + 1], e2 = csr[j + 2], e3 = csr[j + 3];
        int e4 = csr[j + 4], e5 = csr[j + 5], e6 = csr[j + 6], e7 = csr[j + 7];
        HV v0, v1, v2, v3, v4, v5, v6, v7;
        v0.u = *(const uint4*)(T + (size_t)e0 * 128 + c);
        v1.u = *(const uint4*)(T + (size_t)e1 * 128 + c);
        v2.u = *(const uint4*)(T + (size_t)e2 * 128 + c);
        v3.u = *(const uint4*)(T + (size_t)e3 * 128 + c);
        v4.u = *(const uint4*)(T + (size_t)e4 * 128 + c);
        v5.u = *(const uint4*)(T + (size_t)e5 * 128 + c);
        v6.u = *(const uint4*)(T + (size_t)e6 * 128 + c);
        v7.u = *(const uint4*)(T + (size_t)e7 * 128 + c);
#pragma unroll
        for (int q = 0; q < 4; ++q) {
            float2 f0 = __half22float2(v0.h[q]), f1 = __half22float2(v1.h[q]);
            float2 f2 = __half22float2(v2.h[q]), f3 = __half22float2(v3.h[q]);
            float2 f4 = __half22float2(v4.h[q]), f5 = __half22float2(v5.h[q]);
            float2 f6 = __half22float2(v6.h[q]), f7 = __half22float2(v7.h[q]);
            a0[2 * q + 0] += f0.x + f1.x; a0[2 * q + 1] += f0.y + f1.y;
            a1[2 * q + 0] += f2.x + f3.x; a1[2 * q + 1] += f2.y + f3.y;
            a2[2 * q + 0] += f4.x + f5.x; a2[2 * q + 1] += f4.y + f5.y;
            a3[2 * q + 0] += f6.x + f7.x; a3[2 * q + 1] += f6.y + f7.y;
        }
    }
    for (; j < jend; ++j) {
        int e0 = csr[j];
        HV v0;
        v0.u = *(const uint4*)(T + (size_t)e0 * 128 + c);
#pragma unroll
        for (int q = 0; q < 4; ++q) {
            float2 f0 = __half22float2(v0.h[q]);
            a0[2 * q + 0] += f0.x; a0[2 * q + 1] += f0.y;
        }
    }
    float s8[8];
#pragma unroll
    for (int q = 0; q < 8; ++q) s8[q] = a0[q] + a1[q] + a2[q] + a3[q];

    float dd = ddst[n];
    float ds = dsrc[n];
    float h8[8];
#pragma unroll
    for (int q = 0; q < 8; ++q) h8[q] = lrelu(s8[q] * dd + bias[c + q]);
    if (EPI == 0) {
        union HV o;
#pragma unroll
        for (int q = 0; q < 4; ++q)
            o.h[q] = __floats2half2_rn(h8[2 * q] * ds, h8[2 * q + 1] * ds);
        *(uint4*)(Hout + (size_t)n * 128 + c) = o.u;
    } else {
        float s = 0.f;
#pragma unroll
        for (int q = 0; q < 8; ++q) s += h8[q] * wfold[c + q];
#pragma unroll
        for (int o = 8; o > 0; o >>= 1) s += __shfl_xor(s, o);
        if (lane == 0) tv[n] = s * ds;
    }
}

// ---------------- final: z[n]=sum tv[csr], s=z*ddst+c, per-graph mean bins ----------------
__global__ void k_gather_final(const float* __restrict__ tv, const int* __restrict__ csr,
                               const int* __restrict__ off, const float* __restrict__ ddst,
                               const int* __restrict__ gid, const float* __restrict__ cval,
                               float* __restrict__ gsum, float* __restrict__ gcnt, int N) {
    __shared__ float sb[N_GRAPHS], sc[N_GRAPHS];
    for (int i = threadIdx.x; i < N_GRAPHS; i += blockDim.x) { sb[i] = 0.f; sc[i] = 0.f; }
    __syncthreads();
    int n = blockIdx.x * blockDim.x + threadIdx.x;
    if (n < N) {
        int j = off[n], jend = off[n + 1];
        float z = 0.f;
        for (; j < jend; ++j) z += tv[csr[j]];
        float s = z * ddst[n] + cval[0];
        int g = gid[n];
        atomicAdd(&sb[g], s);
        atomicAdd(&sc[g], 1.f);
    }
    __syncthreads();
    for (int j = threadIdx.x; j < N_GRAPHS; j += blockDim.x) {
        if (sc[j] != 0.f) {
            atomicAdd(&gsum[j], sb[j]);
            atomicAdd(&gcnt[j], sc[j]);
        }
    }
}

__global__ void k_final(const float* __restrict__ gsum, const float* __restrict__ gcnt,
                        float* __restrict__ out) {
    int g = threadIdx.x;
    if (g < N_GRAPHS) out[g] = gsum[g] / fmaxf(gcnt[g], 1.0f);
}

extern "C" void kernel_launch(void* const* d_in, const int* in_sizes, int n_in,
                              void* d_out, int out_size, void* d_ws, size_t ws_size,
                              hipStream_t stream) {
    const float* in_feat = (const float*)d_in[0];
    const float* W1   = (const float*)d_in[1];
    const float* b1   = (const float*)d_in[2];
    const float* W2   = (const float*)d_in[3];
    const float* b2   = (const float*)d_in[4];
    const float* W3   = (const float*)d_in[5];
    const float* b3   = (const float*)d_in[6];
    const float* Wout = (const float*)d_in[7];
    const float* bout = (const float*)d_in[8];
    const int* src = (const int*)d_in[9];
    const int* dst = (const int*)d_in[10];
    const int* gid = (const int*)d_in[11];
    const int N = in_sizes[0] / 128;
    const int E = in_sizes[9];
    float* out = (float*)d_out;

    char* ws = (char*)d_ws;
    size_t woff = 0;
    auto alloc = [&](size_t bytes) {
        void* p = ws + woff;
        woff = (woff + bytes + 255) & ~(size_t)255;
        return p;
    };
    const int nchunks = (N + HCHUNK - 1) / HCHUNK;         // 4 for N=100000
    const int NBINS = nchunks * HCHUNK;
    size_t scratch_bytes = (size_t)NBINS * HBLK * 4;       // 33.5 MB
    size_t msg_bytes = (size_t)N * 128 * 2;                // 25.6 MB
    // M (fp16 messages) aliases histogram scratch: scratch dead after k_csrfill2.
    void* region0 = alloc(scratch_bytes > msg_bytes ? scratch_bytes : msg_bytes);
    int*    scratch = (int*)region0;
    __half* M       = (__half*)region0;
    __half* H    = (__half*)alloc(msg_bytes);              // pre-normed activations
    int*   csr   = (int*)alloc((size_t)E * 4);
    int*   degd  = (int*)alloc((size_t)N * 4);
    int*   off   = (int*)alloc((size_t)(N + 1) * 4);
    int*   partials = (int*)alloc(256 * 4);
    float* dsrc  = (float*)alloc((size_t)N * 4);
    float* ddst  = (float*)alloc((size_t)N * 4);
    float* tv    = (float*)alloc((size_t)N * 4);
    float* wfold = (float*)alloc(128 * 4);
    float* cval  = (float*)alloc(4);
    float* gsum  = (float*)alloc(N_GRAPHS * 4);
    float* gcnt  = (float*)alloc(N_GRAPHS * 4);
    __half* w1T  = (__half*)alloc(16384 * 2);
    __half* w2T  = (__half*)alloc(16384 * 2);
    (void)ws_size; (void)n_in; (void)out_size;

    hipMemsetAsync(gsum, 0, N_GRAPHS * 4, stream);
    hipMemsetAsync(gcnt, 0, N_GRAPHS * 4, stream);

    k_fold_w<<<1, 128, 0, stream>>>(W3, b3, Wout, bout, wfold, cval);
    k_wconv<<<1, 256, 0, stream>>>(W1, w1T);
    k_wconv<<<1, 256, 0, stream>>>(W2, w2T);

    // degrees via chunked LDS histograms (no global atomics)
    k_hist<<<nchunks * HBLK, 512, 0, stream>>>(src, scratch, E);
    k_hist_reduce<0><<<(N + 255) / 256, 256, 0, stream>>>(scratch, nullptr, dsrc, N);
    k_hist<<<nchunks * HBLK, 512, 0, stream>>>(dst, scratch, E);
    k_hist_reduce<1><<<(N + 255) / 256, 256, 0, stream>>>(scratch, degd, ddst, N);

    // CSR offsets
    const int nscan = (N + 1023) / 1024;
    k_scanA<<<nscan, 256, 0, stream>>>(degd, off, partials, N);
    k_scanB<<<1, 256, 0, stream>>>(partials, nscan);
    k_scanC<<<nscan, 256, 0, stream>>>(off, partials, N, E);

    // per-block cursors, then counting-sort fill (LDS atomics only)
    k_colscan<<<(NBINS + 255) / 256, 256, 0, stream>>>(scratch, off, NBINS, N);
    k_csrfill2<<<nchunks * HBLK, 512, 0, stream>>>(src, dst, scratch, csr, E);

    const int gblocks = (N + 127) / 128;
    const int agblocks = (N + 15) / 16;

    // layer 1: M = (in_feat * dsrc) @ W1 ; H = prenorm(gather(M), b1)
    k_gemm_mfma<2><<<gblocks, 512, 0, stream>>>(in_feat, M, w1T, dsrc, N);
    k_gather_h<0><<<agblocks, 256, 0, stream>>>(M, H, csr, off, N, ddst, b1, dsrc, nullptr, nullptr);

    // layer 2: M = H @ W2 ; H = prenorm(gather(M), b2)
    k_gemm_mfma<0><<<gblocks, 512, 0, stream>>>(H, M, w2T, nullptr, N);
    k_gather_h<0><<<agblocks, 256, 0, stream>>>(M, H, csr, off, N, ddst, b2, dsrc, nullptr, nullptr);

    // layer 3 (conv2 again): M = H @ W2 ; fused readout gather -> tv
    k_gemm_mfma<0><<<gblocks, 512, 0, stream>>>(H, M, w2T, nullptr, N);
    k_gather_h<1><<<agblocks, 256, 0, stream>>>(M, nullptr, csr, off, N, ddst, b2, dsrc, wfold, tv);

    // readout aggregation + per-graph mean
    k_gather_final<<<(N + 255) / 256, 256, 0, stream>>>(tv, csr, off, ddst, gid, cval, gsum, gcnt, N);
    k_final<<<1, 128, 0, stream>>>(gsum, gcnt, out);
}

// Round 9
// 378.648 us; speedup vs baseline: 1.1978x; 1.1400x over previous
//
#include <hip/hip_runtime.h>
#include <hip/hip_fp16.h>
#include <math.h>

#define N_GRAPHS 100
#define HCHUNK 32768
#define HBLK 64

typedef _Float16 f16x8 __attribute__((ext_vector_type(8)));
typedef __attribute__((ext_vector_type(4))) float f32x4;

__device__ __forceinline__ float lrelu(float v) { return v >= 0.f ? v : 0.1f * v; }

// ---------------- prep: wfold/cval + W1/W2 -> transposed+swizzled fp16 ----------------
__global__ void k_prep(const float* __restrict__ W1, const float* __restrict__ W2,
                       const float* __restrict__ W3, const float* __restrict__ b3,
                       const float* __restrict__ Wout, const float* __restrict__ bout,
                       __half* __restrict__ w1T, __half* __restrict__ w2T,
                       float* __restrict__ wfold, float* __restrict__ cval) {
    if (blockIdx.x == 0) {
        int i = threadIdx.x;
        if (i < 128) {
            float s = 0.f;
            for (int j = 0; j < 64; ++j) s += W3[i * 64 + j] * Wout[j];
            wfold[i] = s;
            if (i == 0) {
                float c = bout[0];
                for (int j = 0; j < 64; ++j) c += b3[j] * Wout[j];
                *cval = c;
            }
        }
    } else {
        const float* W = (blockIdx.x == 1) ? W1 : W2;
        __half* wT = (blockIdx.x == 1) ? w1T : w2T;
        for (int i = threadIdx.x; i < 16384; i += 256) {
            int k = i >> 7, col = i & 127;
            wT[col * 128 + (k ^ ((col & 15) << 3))] = __float2half(W[i]);
        }
    }
}

// ---------------- combined src+dst chunked LDS histograms -> u16 per-block counts ----
// grid = 2 * nchunks * HBLK; first half counts dst, second half counts src.
__global__ __launch_bounds__(512, 1)
void k_hist2(const int* __restrict__ src, const int* __restrict__ dst,
             unsigned short* __restrict__ ssrc, unsigned short* __restrict__ sdst,
             int E, int half) {
    __shared__ int h[HCHUNK];   // 128 KiB
    int id = blockIdx.x;
    const int* keys;
    unsigned short* outbase;
    if (id < half) { keys = dst; outbase = sdst; }
    else           { keys = src; outbase = ssrc; id -= half; }
    const int c = id / HBLK;
    const int b = id % HBLK;
    const int base = c * HCHUNK;
    for (int i = threadIdx.x; i < HCHUNK; i += 512) h[i] = 0;
    __syncthreads();
    for (int i = b * 512 + threadIdx.x; i < E; i += HBLK * 512) {
        unsigned k = (unsigned)(keys[i] - base);
        if (k < HCHUNK) atomicAdd(&h[k], 1);
    }
    __syncthreads();
    unsigned short* outp = outbase + (size_t)(c * HBLK + b) * HCHUNK;
    for (int i = threadIdx.x; i < HCHUNK; i += 512) outp[i] = (unsigned short)h[i];
}

// ---------------- combined reduce: dsrc, degd, ddst ----------------
__global__ void k_reduce2(const unsigned short* __restrict__ ssrc,
                          const unsigned short* __restrict__ sdst,
                          float* __restrict__ dsrc, int* __restrict__ degd,
                          float* __restrict__ ddst, int N) {
    int g = blockIdx.x * blockDim.x + threadIdx.x;
    if (g >= N) return;
    const int c = g >> 15;
    const int p = g & (HCHUNK - 1);
    const unsigned short* cs = ssrc + (size_t)(c * HBLK) * HCHUNK + p;
    const unsigned short* cd = sdst + (size_t)(c * HBLK) * HCHUNK + p;
    int s1 = 0, s2 = 0;
#pragma unroll 8
    for (int b = 0; b < HBLK; ++b) {
        s1 += cs[(size_t)b * HCHUNK];
        s2 += cd[(size_t)b * HCHUNK];
    }
    dsrc[g] = rsqrtf(fmaxf((float)s1, 1.0f));
    degd[g] = s2;
    ddst[g] = rsqrtf(fmaxf((float)s2, 1.0f));
}

// ---------------- exclusive scan over degd -> off (3-kernel) ----------------
__global__ void k_scanA(const int* __restrict__ deg, int* __restrict__ off,
                        int* __restrict__ partials, int N) {
    __shared__ int ts[256];
    const int t = threadIdx.x;
    const int base = blockIdx.x * 1024 + t * 4;
    int v0 = (base + 0 < N) ? deg[base + 0] : 0;
    int v1 = (base + 1 < N) ? deg[base + 1] : 0;
    int v2 = (base + 2 < N) ? deg[base + 2] : 0;
    int v3 = (base + 3 < N) ? deg[base + 3] : 0;
    int s = v0 + v1 + v2 + v3;
    ts[t] = s;
    __syncthreads();
    for (int o = 1; o < 256; o <<= 1) {
        int y = (t >= o) ? ts[t - o] : 0;
        __syncthreads();
        ts[t] += y;
        __syncthreads();
    }
    int excl = ts[t] - s;
    if (base + 0 < N) off[base + 0] = excl;
    if (base + 1 < N) off[base + 1] = excl + v0;
    if (base + 2 < N) off[base + 2] = excl + v0 + v1;
    if (base + 3 < N) off[base + 3] = excl + v0 + v1 + v2;
    if (t == 255) partials[blockIdx.x] = ts[255];
}

// scanB also zero-inits gsum/gcnt (replaces two memsets)
__global__ void k_scanB(int* __restrict__ partials, int nb,
                        float* __restrict__ gsum, float* __restrict__ gcnt) {
    __shared__ int ps[256];
    const int t = threadIdx.x;
    if (t < N_GRAPHS) { gsum[t] = 0.f; gcnt[t] = 0.f; }
    int v = (t < nb) ? partials[t] : 0;
    ps[t] = v;
    __syncthreads();
    for (int o = 1; o < 256; o <<= 1) {
        int y = (t >= o) ? ps[t - o] : 0;
        __syncthreads();
        ps[t] += y;
        __syncthreads();
    }
    if (t < nb) partials[t] = ps[t] - v;
}

__global__ void k_scanC(int* __restrict__ off, const int* __restrict__ partials, int N, int E) {
    const int t = threadIdx.x;
    const int base = blockIdx.x * 1024 + t * 4;
    const int add = partials[blockIdx.x];
#pragma unroll
    for (int q = 0; q < 4; ++q) {
        int idx = base + q;
        if (idx < N) off[idx] += add;
    }
    if (blockIdx.x == 0 && t == 0) off[N] = E;
}

// ---------------- in-place u16 column prefix over blocks ----------------
__global__ void k_colscan16(unsigned short* __restrict__ sdst, int NBINS) {
    int g = blockIdx.x * blockDim.x + threadIdx.x;
    if (g >= NBINS) return;
    const int c = g >> 15;
    const int p = g & (HCHUNK - 1);
    unsigned short* col = sdst + (size_t)(c * HBLK) * HCHUNK + p;
    int run = 0;
    for (int b = 0; b < HBLK; ++b) {
        unsigned short* q = col + (size_t)b * HCHUNK;
        int t = *q;
        *q = (unsigned short)run;
        run += t;
    }
}

// ---------------- CSR fill via LDS cursors (cursor = off + u16 prefix) ----------------
__global__ __launch_bounds__(512, 1)
void k_csrfill2(const int* __restrict__ src, const int* __restrict__ dst,
                const unsigned short* __restrict__ pref, const int* __restrict__ off,
                int* __restrict__ csr, int E, int N) {
    __shared__ int cur[HCHUNK];   // 128 KiB
    const int c = blockIdx.x / HBLK;
    const int b = blockIdx.x % HBLK;
    const int base = c * HCHUNK;
    const unsigned short* my = pref + (size_t)(c * HBLK + b) * HCHUNK;
    for (int i = threadIdx.x; i < HCHUNK; i += 512) {
        int g = base + i;
        cur[i] = ((g < N) ? off[g] : 0) + (int)my[i];
    }
    __syncthreads();
    for (int i = b * 512 + threadIdx.x; i < E; i += HBLK * 512) {
        unsigned k = (unsigned)(dst[i] - base);
        if (k < HCHUNK) {
            int p = atomicAdd(&cur[k], 1);
            csr[p] = src[i];
        }
    }
}

// ---------------- fp16 MFMA GEMM:  M = X @ W ----------------
// PRE==2: X fp32, prenorm x*dinv_src (layer 1).  PRE==0: X fp16, pure GEMM.
template <int PRE>
__global__ __launch_bounds__(512, 2)
void k_gemm_mfma(const void* __restrict__ Xv, __half* __restrict__ Y,
                 const __half* __restrict__ wT, const float* __restrict__ dinv_src,
                 int N) {
    __shared__ __half Xs[128 * 128];  // 32 KiB
    __shared__ __half Ws[128 * 128];  // 32 KiB
    const int t = threadIdx.x;
    const int r0 = blockIdx.x * 128;

    for (int i = t; i < 2048; i += 512) ((float4*)Ws)[i] = ((const float4*)wT)[i];

    if (PRE == 2) {
        const float* X = (const float*)Xv;
        for (int i = t; i < 4096; i += 512) {
            int row = i >> 5;
            int g4 = (i & 31) << 2;
            int grow = r0 + row;
            float4 v = make_float4(0.f, 0.f, 0.f, 0.f);
            if (grow < N) {
                v = ((const float4*)(X + (size_t)grow * 128))[i & 31];
                float ds = dinv_src[grow];
                v.x *= ds; v.y *= ds; v.z *= ds; v.w *= ds;
            }
            union { float2 f; __half2 h[2]; } pk;
            pk.h[0] = __floats2half2_rn(v.x, v.y);
            pk.h[1] = __floats2half2_rn(v.z, v.w);
            *(float2*)&Xs[row * 128 + (g4 ^ ((row & 15) << 3))] = pk.f;
        }
    } else {
        const __half* X = (const __half*)Xv;
        for (int i = t; i < 2048; i += 512) {
            int row = i >> 4;
            int g8 = (i & 15) << 3;
            int grow = r0 + row;
            uint4 v = make_uint4(0u, 0u, 0u, 0u);
            if (grow < N) v = ((const uint4*)(X + (size_t)grow * 128))[i & 15];
            *(uint4*)&Xs[row * 128 + (g8 ^ ((row & 15) << 3))] = v;
        }
    }
    __syncthreads();

    const int w = t >> 6;
    const int wm = w & 3;          // rows 32*wm..+31
    const int wn = w >> 2;         // cols 64*wn..+63
    const int lane = t & 63;
    const int lr = lane & 15;
    const int lg = lane >> 4;

    f32x4 acc[2][4];
#pragma unroll
    for (int mi = 0; mi < 2; ++mi)
#pragma unroll
        for (int ni = 0; ni < 4; ++ni) acc[mi][ni] = (f32x4){0.f, 0.f, 0.f, 0.f};

#pragma unroll
    for (int ks = 0; ks < 4; ++ks) {
        const int k0 = 32 * ks + 4 * lg;
        union F { float2 f[2]; f16x8 v; };
        F a[2];
#pragma unroll
        for (int mi = 0; mi < 2; ++mi) {
            int row = 32 * wm + 16 * mi + lr;
            int sw = (row & 15) << 3;
            a[mi].f[0] = *(const float2*)&Xs[row * 128 + (k0 ^ sw)];
            a[mi].f[1] = *(const float2*)&Xs[row * 128 + ((k0 + 16) ^ sw)];
        }
#pragma unroll
        for (int ni = 0; ni < 4; ++ni) {
            int colv = 64 * wn + 16 * ni + lr;
            int sw = (colv & 15) << 3;
            F b;
            b.f[0] = *(const float2*)&Ws[colv * 128 + (k0 ^ sw)];
            b.f[1] = *(const float2*)&Ws[colv * 128 + ((k0 + 16) ^ sw)];
#pragma unroll
            for (int mi = 0; mi < 2; ++mi) {
                acc[mi][ni] = __builtin_amdgcn_mfma_f32_16x16x32_f16(a[mi].v, b.v, acc[mi][ni], 0, 0, 0);
            }
        }
    }

    // epilogue: bounce C through LDS (reuse Xs) for coalesced 16B stores
    __syncthreads();
#pragma unroll
    for (int mi = 0; mi < 2; ++mi)
#pragma unroll
        for (int r = 0; r < 4; ++r) {
            int row = 32 * wm + 16 * mi + 4 * lg + r;
#pragma unroll
            for (int ni = 0; ni < 4; ++ni)
                Xs[row * 128 + 64 * wn + 16 * ni + lr] = __float2half(acc[mi][ni][r]);
        }
    __syncthreads();
    for (int i = t; i < 2048; i += 512) {
        int row = i >> 4;
        int grow = r0 + row;
        if (grow < N) {
            int col8 = (i & 15) << 3;
            *(uint4*)(Y + (size_t)grow * 128 + col8) = *(const uint4*)&Xs[row * 128 + col8];
        }
    }
}

// ---------------- CSR gather (fp16 msgs), half-wave per node, 4-edge unroll ----------
// EPI==0: H[n] = fp16( lrelu(agg*ddst + bias) * dsrc )
// EPI==1: tv[n] = dsrc * ( lrelu(agg*ddst + bias) . wfold )
template <int EPI>
__global__ __launch_bounds__(256)
void k_gather_h(const __half* __restrict__ T, __half* __restrict__ Hout,
                const int* __restrict__ csr, const int* __restrict__ off, int N,
                const float* __restrict__ ddst, const float* __restrict__ bias,
                const float* __restrict__ dsrc, const float* __restrict__ wfold,
                float* __restrict__ tv) {
    int n = blockIdx.x * 8 + (threadIdx.x >> 5);
    if (n >= N) return;
    const int lane = threadIdx.x & 31;
    const int c = lane << 2;      // 4 halfs per lane (8 B)
    int j = off[n];
    const int jend = off[n + 1];
    float4 a0 = make_float4(0.f, 0.f, 0.f, 0.f);
    float4 a1 = make_float4(0.f, 0.f, 0.f, 0.f);
    union H4 { float2 raw; __half2 hh[2]; };
    for (; j + 4 <= jend; j += 4) {
        int i0 = csr[j], i1 = csr[j + 1], i2 = csr[j + 2], i3 = csr[j + 3];
        H4 v0, v1, v2, v3;
        v0.raw = *(const float2*)(T + (size_t)i0 * 128 + c);
        v1.raw = *(const float2*)(T + (size_t)i1 * 128 + c);
        v2.raw = *(const float2*)(T + (size_t)i2 * 128 + c);
        v3.raw = *(const float2*)(T + (size_t)i3 * 128 + c);
        float2 x0 = __half22float2(v0.hh[0]), y0 = __half22float2(v0.hh[1]);
        float2 x1 = __half22float2(v1.hh[0]), y1 = __half22float2(v1.hh[1]);
        float2 x2 = __half22float2(v2.hh[0]), y2 = __half22float2(v2.hh[1]);
        float2 x3 = __half22float2(v3.hh[0]), y3 = __half22float2(v3.hh[1]);
        a0.x += x0.x + x1.x; a0.y += x0.y + x1.y; a0.z += y0.x + y1.x; a0.w += y0.y + y1.y;
        a1.x += x2.x + x3.x; a1.y += x2.y + x3.y; a1.z += y2.x + y3.x; a1.w += y2.y + y3.y;
    }
    for (; j < jend; ++j) {
        int i0 = csr[j];
        H4 v0;
        v0.raw = *(const float2*)(T + (size_t)i0 * 128 + c);
        float2 x0 = __half22float2(v0.hh[0]), y0 = __half22float2(v0.hh[1]);
        a0.x += x0.x; a0.y += x0.y; a0.z += y0.x; a0.w += y0.y;
    }
    float4 a = make_float4(a0.x + a1.x, a0.y + a1.y, a0.z + a1.z, a0.w + a1.w);
    float dd = ddst[n];
    float ds = dsrc[n];
    float h0 = lrelu(a.x * dd + bias[c + 0]);
    float h1 = lrelu(a.y * dd + bias[c + 1]);
    float h2 = lrelu(a.z * dd + bias[c + 2]);
    float h3 = lrelu(a.w * dd + bias[c + 3]);
    if (EPI == 0) {
        union H4 o;
        o.hh[0] = __floats2half2_rn(h0 * ds, h1 * ds);
        o.hh[1] = __floats2half2_rn(h2 * ds, h3 * ds);
        *(float2*)(Hout + (size_t)n * 128 + c) = o.raw;
    } else {
        float s = h0 * wfold[c + 0] + h1 * wfold[c + 1] + h2 * wfold[c + 2] + h3 * wfold[c + 3];
#pragma unroll
        for (int o = 16; o > 0; o >>= 1) s += __shfl_xor(s, o);
        if (lane == 0) tv[n] = s * ds;
    }
}

// ---------------- final: z[n]=sum tv[csr], s=z*ddst+c, per-graph mean bins ----------------
__global__ void k_gather_final(const float* __restrict__ tv, const int* __restrict__ csr,
                               const int* __restrict__ off, const float* __restrict__ ddst,
                               const int* __restrict__ gid, const float* __restrict__ cval,
                               float* __restrict__ gsum, float* __restrict__ gcnt, int N) {
    __shared__ float sb[N_GRAPHS], sc[N_GRAPHS];
    for (int i = threadIdx.x; i < N_GRAPHS; i += blockDim.x) { sb[i] = 0.f; sc[i] = 0.f; }
    __syncthreads();
    int n = blockIdx.x * blockDim.x + threadIdx.x;
    if (n < N) {
        int j = off[n], jend = off[n + 1];
        float z = 0.f;
        for (; j < jend; ++j) z += tv[csr[j]];
        float s = z * ddst[n] + cval[0];
        int g = gid[n];
        atomicAdd(&sb[g], s);
        atomicAdd(&sc[g], 1.f);
    }
    __syncthreads();
    for (int j = threadIdx.x; j < N_GRAPHS; j += blockDim.x) {
        if (sc[j] != 0.f) {
            atomicAdd(&gsum[j], sb[j]);
            atomicAdd(&gcnt[j], sc[j]);
        }
    }
}

__global__ void k_final(const float* __restrict__ gsum, const float* __restrict__ gcnt,
                        float* __restrict__ out) {
    int g = threadIdx.x;
    if (g < N_GRAPHS) out[g] = gsum[g] / fmaxf(gcnt[g], 1.0f);
}

extern "C" void kernel_launch(void* const* d_in, const int* in_sizes, int n_in,
                              void* d_out, int out_size, void* d_ws, size_t ws_size,
                              hipStream_t stream) {
    const float* in_feat = (const float*)d_in[0];
    const float* W1   = (const float*)d_in[1];
    const float* b1   = (const float*)d_in[2];
    const float* W2   = (const float*)d_in[3];
    const float* b2   = (const float*)d_in[4];
    const float* W3   = (const float*)d_in[5];
    const float* b3   = (const float*)d_in[6];
    const float* Wout = (const float*)d_in[7];
    const float* bout = (const float*)d_in[8];
    const int* src = (const int*)d_in[9];
    const int* dst = (const int*)d_in[10];
    const int* gid = (const int*)d_in[11];
    const int N = in_sizes[0] / 128;
    const int E = in_sizes[9];
    float* out = (float*)d_out;

    char* ws = (char*)d_ws;
    size_t woff = 0;
    auto alloc = [&](size_t bytes) {
        void* p = ws + woff;
        woff = (woff + bytes + 255) & ~(size_t)255;
        return p;
    };
    const int nchunks = (N + HCHUNK - 1) / HCHUNK;         // 4 for N=100000
    const int NBINS = nchunks * HCHUNK;
    size_t scr_one = (size_t)NBINS * HBLK * 2;             // u16: 16.78 MB each
    size_t msg_bytes = (size_t)N * 128 * 2;                // 25.6 MB
    size_t r0_bytes = 2 * scr_one > msg_bytes ? 2 * scr_one : msg_bytes;
    // M (fp16 messages) aliases histogram scratch (dead after csrfill).
    void* region0 = alloc(r0_bytes);
    unsigned short* sdst = (unsigned short*)region0;
    unsigned short* ssrc = (unsigned short*)((char*)region0 + scr_one);
    __half* M            = (__half*)region0;
    __half* H    = (__half*)alloc(msg_bytes);              // pre-normed activations
    int*   csr   = (int*)alloc((size_t)E * 4);
    int*   degd  = (int*)alloc((size_t)N * 4);
    int*   off   = (int*)alloc((size_t)(N + 1) * 4);
    int*   partials = (int*)alloc(256 * 4);
    float* dsrc  = (float*)alloc((size_t)N * 4);
    float* ddst  = (float*)alloc((size_t)N * 4);
    float* tv    = (float*)alloc((size_t)N * 4);
    float* wfold = (float*)alloc(128 * 4);
    float* cval  = (float*)alloc(4);
    float* gsum  = (float*)alloc(N_GRAPHS * 4);
    float* gcnt  = (float*)alloc(N_GRAPHS * 4);
    __half* w1T  = (__half*)alloc(16384 * 2);
    __half* w2T  = (__half*)alloc(16384 * 2);
    (void)ws_size; (void)n_in; (void)out_size;

    const int half = nchunks * HBLK;                       // 256

    k_prep<<<3, 256, 0, stream>>>(W1, W2, W3, b3, Wout, bout, w1T, w2T, wfold, cval);

    // combined src+dst degree histograms (u16 per-block counts)
    k_hist2<<<2 * half, 512, 0, stream>>>(src, dst, ssrc, sdst, E, half);
    k_reduce2<<<(N + 255) / 256, 256, 0, stream>>>(ssrc, sdst, dsrc, degd, ddst, N);

    // CSR offsets
    const int nscan = (N + 1023) / 1024;
    k_scanA<<<nscan, 256, 0, stream>>>(degd, off, partials, N);
    k_scanB<<<1, 256, 0, stream>>>(partials, nscan, gsum, gcnt);
    k_scanC<<<nscan, 256, 0, stream>>>(off, partials, N, E);

    // in-place u16 prefix, then counting-sort fill (LDS atomics only)
    k_colscan16<<<(NBINS + 255) / 256, 256, 0, stream>>>(sdst, NBINS);
    k_csrfill2<<<half, 512, 0, stream>>>(src, dst, sdst, off, csr, E, N);

    const int gblocks = (N + 127) / 128;
    const int agblocks = (N + 7) / 8;

    // layer 1: M = (in_feat * dsrc) @ W1 ; H = prenorm(gather(M), b1)
    k_gemm_mfma<2><<<gblocks, 512, 0, stream>>>(in_feat, M, w1T, dsrc, N);
    k_gather_h<0><<<agblocks, 256, 0, stream>>>(M, H, csr, off, N, ddst, b1, dsrc, nullptr, nullptr);

    // layer 2: M = H @ W2 ; H = prenorm(gather(M), b2)
    k_gemm_mfma<0><<<gblocks, 512, 0, stream>>>(H, M, w2T, nullptr, N);
    k_gather_h<0><<<agblocks, 256, 0, stream>>>(M, H, csr, off, N, ddst, b2, dsrc, nullptr, nullptr);

    // layer 3 (conv2 again): M = H @ W2 ; fused readout gather -> tv
    k_gemm_mfma<0><<<gblocks, 512, 0, stream>>>(H, M, w2T, nullptr, N);
    k_gather_h<1><<<agblocks, 256, 0, stream>>>(M, nullptr, csr, off, N, ddst, b2, dsrc, wfold, tv);

    // readout aggregation + per-graph mean
    k_gather_final<<<(N + 255) / 256, 256, 0, stream>>>(tv, csr, off, ddst, gid, cval, gsum, gcnt, N);
    k_final<<<1, 128, 0, stream>>>(gsum, gcnt, out);
}